// Round 12
// baseline (251.909 us; speedup 1.0000x reference)
//
#include <hip/hip_runtime.h>
#include <math.h>

typedef short s16x8 __attribute__((ext_vector_type(8)));
typedef short s16x4 __attribute__((ext_vector_type(4)));
typedef float f32x4 __attribute__((ext_vector_type(4)));

__device__ __forceinline__ void bsplit(float x, short& hi, short& lo) {
    unsigned u  = __float_as_uint(x);
    unsigned uh = u & 0xFFFF0000u;
    hi = (short)(uh >> 16);
    float r = x - __uint_as_float(uh);
    lo = (short)(__float_as_uint(r) >> 16);
}

#define MFMA_B16(A, B, C) __builtin_amdgcn_mfma_f32_16x16x32_bf16((A), (B), (C), 0, 0, 0)

// Single fused kernel: 1 batch/block, 1024 thr (16 waves), single-role waves:
//   waves 0-6  : L2 o-tile n2=w      (hold w2 frags only)
//   waves 7-11 : L3 o3-tile n3=w-7   (hold w3 frags only)
//   waves 12-15: h1 gen              (w1 from LDS, no frags)
// h1/h2 double-buffered -> gen(T+1) || L2(T) || L3(T-1) in ONE phase,
// 10 barriers per batch instead of 24. Bodies identical to R10 (verified).
__global__ __launch_bounds__(1024, 4)
void ds_all(const float* __restrict__ dyn, const float* __restrict__ stat,
            const float* __restrict__ pw1, const float* __restrict__ pb1,
            const float* __restrict__ pw2, const float* __restrict__ pb2,
            const float* __restrict__ pw3, const float* __restrict__ pb3,
            const float* __restrict__ rw1, const float* __restrict__ rb1,
            const float* __restrict__ rw2, const float* __restrict__ rb2,
            const float* __restrict__ rw3, const float* __restrict__ rb3,
            const float* __restrict__ qw1, const float* __restrict__ qb1,
            const float* __restrict__ qw2, const float* __restrict__ qb2,
            const float* __restrict__ qw3, const float* __restrict__ qb3,
            float* __restrict__ out) {
    const int tid = threadIdx.x;
    const int w = tid >> 6, l = tid & 63, ln = l & 15, l4 = l >> 4;
    const int b = blockIdx.x;

    __shared__ __align__(16) float xs[384];
    __shared__ __align__(16) float sw1[512];
    __shared__ short h1H[4096], h1L[4096];   // 2 bufs x [16 el][128 k], swizzled
    __shared__ short h2H[4096], h2L[4096];   // 2 bufs x [16 el][128 o], swizzled
    __shared__ __align__(16) float pooledS[80];
    __shared__ __align__(16) float r1s[64], r2s[64], xcat[48], q1s[200], q2s[104];
    __shared__ float logits[3];

    // ---- stage dyn[b]; pack w1|b1 -> sw1; zero h2 pad cols both buffers ----
    if (tid < 96)
        *(f32x4*)(xs + tid * 4) = *(const f32x4*)(dyn + (size_t)b * 384 + tid * 4);
    if (tid >= 128 && tid < 256) {
        const int t = tid - 128;
        f32x4 v = 0.f;
        if (t < 120) { v.x = pw1[t*3]; v.y = pw1[t*3+1]; v.z = pw1[t*3+2]; v.w = pb1[t]; }
        *(f32x4*)(sw1 + t * 4) = v;
    }
    if (tid >= 256 && tid < 512) {
        const int t = tid - 256;               // 0..255
        const int buf = t >> 7, hl = (t >> 6) & 1, u = t & 63;
        const int row = u >> 2, q = u & 3;
        const int col = (112 + q * 4) ^ ((row & 7) << 3);
        short* dst = hl ? h2L : h2H;
        s16x4 z = 0;
        *(s16x4*)(dst + buf * 2048 + row * 128 + col) = z;
    }

    // ---- stationary weight frags, one role per wave ----
    s16x8 wh0=0,wh1=0,wh2=0,wh3=0, wl0=0,wl1=0,wl2=0,wl3=0;
    f32x4 bbv = 0.f;
    if (w < 7) {
        const int arow = 16 * w + ln;
        #define LDW2(KS, DH, DL) do { s16x8 vh, vl;                             \
            _Pragma("unroll")                                                   \
            for (int j = 0; j < 8; ++j) {                                       \
                const int c = (KS) * 32 + l4 * 8 + j;                           \
                float v = (arow < 100 && c < 120) ? pw2[arow * 120 + c] : 0.f;  \
                short hi, lo; bsplit(v, hi, lo); vh[j] = hi; vl[j] = lo;        \
            } DH = vh; DL = vl; } while (0)
        LDW2(0, wh0, wl0); LDW2(1, wh1, wl1);
        LDW2(2, wh2, wl2); LDW2(3, wh3, wl3);
        #undef LDW2
        const int o0 = 16 * w + 4 * l4;
        #pragma unroll
        for (int r = 0; r < 4; ++r) bbv[r] = (o0 + r < 100) ? pb2[o0 + r] : 0.f;
    } else if (w < 12) {
        const int arow = 16 * (w - 7) + ln;
        #define LDW3(KS, DH, DL) do { s16x8 vh, vl;                             \
            _Pragma("unroll")                                                   \
            for (int j = 0; j < 8; ++j) {                                       \
                const int c = (KS) * 32 + l4 * 8 + j;                           \
                float v = (c < 100) ? pw3[arow * 100 + c] : 0.f;                \
                short hi, lo; bsplit(v, hi, lo); vh[j] = hi; vl[j] = lo;        \
            } DH = vh; DL = vl; } while (0)
        LDW3(0, wh0, wl0); LDW3(1, wh1, wl1);
        LDW3(2, wh2, wl2); LDW3(3, wh3, wl3);
        #undef LDW3
        bbv = *(const f32x4*)(pb3 + 16 * (w - 7) + 4 * l4);
    }
    __syncthreads();

    const int swzR = (ln & 7) << 3;
    const int tg = tid & 255, grow = tg >> 4, gk0 = (tg & 15) * 8;
    float pool0 = 0.f, pool1 = 0.f, pool2 = 0.f, pool3 = 0.f;

    // gen body: tile TN -> h1 buffer at short-offset BUF
    #define GENT(TN, BUF) do {                                                  \
        const int el = 16 * (TN) + grow;                                        \
        const float x0 = xs[el*3], x1 = xs[el*3+1], x2 = xs[el*3+2];            \
        s16x8 vh, vl;                                                           \
        _Pragma("unroll")                                                       \
        for (int j = 0; j < 8; ++j) {                                           \
            f32x4 c = *(const f32x4*)(sw1 + (gk0 + j) * 4);                     \
            float v = fmaf(x0, c.x, fmaf(x1, c.y, fmaf(x2, c.z, c.w)));         \
            v = fmaxf(v, 0.f);                                                  \
            short hi, lo; bsplit(v, hi, lo); vh[j] = hi; vl[j] = lo;            \
        }                                                                       \
        const int idx = (BUF) + grow * 128 + (gk0 ^ ((grow & 7) << 3));         \
        *(s16x8*)(h1H + idx) = vh;                                              \
        *(s16x8*)(h1L + idx) = vl;                                              \
    } while (0)

    // ---- pipeline prologue: gen tile 0 into buffer 0 ----
    if (w >= 12) GENT(0, 0);
    __syncthreads();

    #define L2K(BUF, KS, WH, WL) do {                                           \
        const int bidx = (BUF) + ln * 128 + (((KS) * 32 + l4 * 8) ^ swzR);      \
        const s16x8 bh = *(const s16x8*)(h1H + bidx);                           \
        const s16x8 bl = *(const s16x8*)(h1L + bidx);                           \
        a2h = MFMA_B16(WH, bh, a2h);                                            \
        a2x = MFMA_B16(WH, bl, a2x);                                            \
        a2x = MFMA_B16(WL, bh, a2x);                                            \
    } while (0)
    #define L3K(BUF, KS, WH, WL) do {                                           \
        const int bidx = (BUF) + ln * 128 + (((KS) * 32 + l4 * 8) ^ swzR);      \
        const s16x8 bh = *(const s16x8*)(h2H + bidx);                           \
        const s16x8 bl = *(const s16x8*)(h2L + bidx);                           \
        a3  = MFMA_B16(WH, bh, a3);                                             \
        a3x = MFMA_B16(WH, bl, a3x);                                            \
        a3x = MFMA_B16(WL, bh, a3x);                                            \
    } while (0)

    // ---- main pipeline: T=0..8; cb = buf(T), ob = buf(T+1) = buf(T-1) ----
    #pragma unroll 1
    for (int T = 0; T <= 8; ++T) {
        const int cb = (T & 1) << 11;        // current buffer short-offset
        const int ob = 2048 - cb;            // other buffer
        if (w >= 12) {
            if (T < 7) {
                const int TN = T + 1;
                GENT(TN, ob);
            }
        } else if (w < 7) {
            if (T < 8) {
                f32x4 a2h = 0.f, a2x = 0.f;
                L2K(cb, 0, wh0, wl0); L2K(cb, 1, wh1, wl1);
                L2K(cb, 2, wh2, wl2); L2K(cb, 3, wh3, wl3);
                s16x4 oh, ol;
                #pragma unroll
                for (int r = 0; r < 4; ++r) {
                    float v = fmaxf(a2h[r] + a2x[r] + bbv[r], 0.f);
                    short hi, lo; bsplit(v, hi, lo);
                    oh[r] = hi; ol[r] = lo;
                }
                const int idx2 = cb + ln * 128 + ((16 * w + 4 * l4) ^ swzR);
                *(s16x4*)(h2H + idx2) = oh;
                *(s16x4*)(h2L + idx2) = ol;
            }
        } else {
            if (T >= 1) {
                f32x4 a3 = 0.f, a3x = 0.f;
                L3K(ob, 0, wh0, wl0); L3K(ob, 1, wh1, wl1);
                L3K(ob, 2, wh2, wl2); L3K(ob, 3, wh3, wl3);
                pool0 += fmaxf(a3[0] + a3x[0] + bbv[0], 0.f);
                pool1 += fmaxf(a3[1] + a3x[1] + bbv[1], 0.f);
                pool2 += fmaxf(a3[2] + a3x[2] + bbv[2], 0.f);
                pool3 += fmaxf(a3[3] + a3x[3] + bbv[3], 0.f);
            }
        }
        __syncthreads();
    }
    #undef GENT
    #undef L2K
    #undef L3K

    // ---- pool reduce over ln, write pooledS ----
    if (w >= 7 && w < 12) {
        #pragma unroll
        for (int d = 1; d < 16; d <<= 1) {
            pool0 += __shfl_xor(pool0, d);
            pool1 += __shfl_xor(pool1, d);
            pool2 += __shfl_xor(pool2, d);
            pool3 += __shfl_xor(pool3, d);
        }
        if (ln == 0) {
            const int o0 = 16 * (w - 7) + 4 * l4;
            pooledS[o0 + 0] = pool0;
            pooledS[o0 + 1] = pool1;
            pooledS[o0 + 2] = pool2;
            pooledS[o0 + 3] = pool3;
        }
    }
    __syncthreads();

    // ---- fused tail (R10-verified) ----
    if (tid < 60) {
        float a = rb1[tid];
        for (int k = 0; k < 80; k += 4) {
            f32x4 pv = *(const f32x4*)(pooledS + k);
            f32x4 wv = *(const f32x4*)(rw1 + tid * 80 + k);
            a += pv.x * wv.x + pv.y * wv.y + pv.z * wv.z + pv.w * wv.w;
        }
        r1s[tid] = fmaxf(a, 0.0f);
    }
    __syncthreads();
    if (tid < 60) {
        float a = rb2[tid];
        for (int k = 0; k < 60; k += 4) {
            f32x4 pv = *(const f32x4*)(r1s + k);
            f32x4 wv = *(const f32x4*)(rw2 + tid * 60 + k);
            a += pv.x * wv.x + pv.y * wv.y + pv.z * wv.z + pv.w * wv.w;
        }
        r2s[tid] = fmaxf(a, 0.0f);
    }
    __syncthreads();
    if (tid < 40) {
        float a = rb3[tid];
        for (int k = 0; k < 60; k += 4) {
            f32x4 pv = *(const f32x4*)(r2s + k);
            f32x4 wv = *(const f32x4*)(rw3 + tid * 60 + k);
            a += pv.x * wv.x + pv.y * wv.y + pv.z * wv.z + pv.w * wv.w;
        }
        xcat[tid] = a;
    }
    if (tid >= 40 && tid < 43) xcat[tid] = stat[(size_t)b * 3 + (tid - 40)];
    __syncthreads();
    if (tid < 200) {
        float a = qb1[tid];
        const float* wv = qw1 + tid * 43;
        for (int k = 0; k < 43; ++k) a += xcat[k] * wv[k];
        q1s[tid] = fmaxf(a, 0.0f);
    }
    __syncthreads();
    if (tid < 100) {
        float a = qb2[tid];
        for (int k = 0; k < 200; k += 4) {
            f32x4 pv = *(const f32x4*)(q1s + k);
            f32x4 wv = *(const f32x4*)(qw2 + tid * 200 + k);
            a += pv.x * wv.x + pv.y * wv.y + pv.z * wv.z + pv.w * wv.w;
        }
        q2s[tid] = fmaxf(a, 0.0f);
    }
    __syncthreads();
    if (tid < 96) {
        int o = tid >> 5, l2 = tid & 31;
        float a = 0.0f;
        for (int k = l2; k < 100; k += 32) a += q2s[k] * qw3[o * 100 + k];
        #pragma unroll
        for (int d = 16; d > 0; d >>= 1) a += __shfl_down(a, d, 32);
        if (l2 == 0) logits[o] = a + qb3[o];
    }
    __syncthreads();
    if (tid < 3) {
        float l0 = logits[0], l1 = logits[1], l2v = logits[2];
        float m  = fmaxf(l0, fmaxf(l1, l2v));
        float e0 = __expf(l0 - m), e1 = __expf(l1 - m), e2 = __expf(l2v - m);
        float inv = 1.0f / (e0 + e1 + e2);
        float mine = (tid == 0) ? e0 : ((tid == 1) ? e1 : e2);
        out[(size_t)b * 3 + tid] = mine * inv;
    }
}

extern "C" void kernel_launch(void* const* d_in, const int* in_sizes, int n_in,
                              void* d_out, int out_size, void* d_ws, size_t ws_size,
                              hipStream_t stream) {
    const float* dyn  = (const float*)d_in[0];
    const float* stat = (const float*)d_in[1];
    const float* pw1  = (const float*)d_in[2];
    const float* pb1  = (const float*)d_in[3];
    const float* pw2  = (const float*)d_in[4];
    const float* pb2  = (const float*)d_in[5];
    const float* pw3  = (const float*)d_in[6];
    const float* pb3  = (const float*)d_in[7];
    const float* rw1  = (const float*)d_in[8];
    const float* rb1  = (const float*)d_in[9];
    const float* rw2  = (const float*)d_in[10];
    const float* rb2  = (const float*)d_in[11];
    const float* rw3  = (const float*)d_in[12];
    const float* rb3  = (const float*)d_in[13];
    const float* qw1  = (const float*)d_in[14];
    const float* qb1  = (const float*)d_in[15];
    const float* qw2  = (const float*)d_in[16];
    const float* qb2  = (const float*)d_in[17];
    const float* qw3  = (const float*)d_in[18];
    const float* qb3  = (const float*)d_in[19];
    float* out = (float*)d_out;

    const int B = in_sizes[0] / 384;   // 2048
    ds_all<<<dim3(B), dim3(1024), 0, stream>>>(dyn, stat,
        pw1, pb1, pw2, pb2, pw3, pb3,
        rw1, rb1, rw2, rb2, rw3, rb3,
        qw1, qb1, qw2, qb2, qw3, qb3, out);
}

// Round 13
// 246.628 us; speedup vs baseline: 1.0214x; 1.0214x over previous
//
#include <hip/hip_runtime.h>
#include <math.h>

typedef short s16x8 __attribute__((ext_vector_type(8)));
typedef short s16x4 __attribute__((ext_vector_type(4)));
typedef float f32x4 __attribute__((ext_vector_type(4)));

__device__ __forceinline__ void bsplit(float x, short& hi, short& lo) {
    unsigned u  = __float_as_uint(x);
    unsigned uh = u & 0xFFFF0000u;
    hi = (short)(uh >> 16);
    float r = x - __uint_as_float(uh);
    lo = (short)(__float_as_uint(r) >> 16);
}

#define MFMA_B16(A, B, C) __builtin_amdgcn_mfma_f32_16x16x32_bf16((A), (B), (C), 0, 0, 0)

// Single fused kernel: 1 batch/block, 512 thr (8 waves), R10 roles/bodies,
// but h1 AND h2 double-buffered -> 3-stage software pipeline with ONE barrier
// per tile: phase T = { gen(T) || L2(T-1) || L3(T-2) }; 10 barriers vs 24.
__global__ __launch_bounds__(512, 2)
void ds_all(const float* __restrict__ dyn, const float* __restrict__ stat,
            const float* __restrict__ pw1, const float* __restrict__ pb1,
            const float* __restrict__ pw2, const float* __restrict__ pb2,
            const float* __restrict__ pw3, const float* __restrict__ pb3,
            const float* __restrict__ rw1, const float* __restrict__ rb1,
            const float* __restrict__ rw2, const float* __restrict__ rb2,
            const float* __restrict__ rw3, const float* __restrict__ rb3,
            const float* __restrict__ qw1, const float* __restrict__ qb1,
            const float* __restrict__ qw2, const float* __restrict__ qb2,
            const float* __restrict__ qw3, const float* __restrict__ qb3,
            float* __restrict__ out) {
    const int tid = threadIdx.x;
    const int w = tid >> 6, l = tid & 63, ln = l & 15, l4 = l >> 4;
    const int b = blockIdx.x;

    __shared__ __align__(16) float xs[384];
    __shared__ short h1H[4096], h1L[4096];   // 2 bufs x [16 el][128 k], swizzled
    __shared__ short h2H[4096], h2L[4096];   // 2 bufs x [16 el][128 o], swizzled
    __shared__ __align__(16) float pooledS[80];
    __shared__ __align__(16) float r1s[64], r2s[64], xcat[48], q1s[200], q2s[104];
    __shared__ float logits[3];

    // ---- stage dyn[b] ----
    if (tid < 96)
        *(f32x4*)(xs + tid * 4) = *(const f32x4*)(dyn + (size_t)b * 384 + tid * 4);

    // ---- zero h2 pad cols 112..127 in BOTH buffers ----
    if (tid >= 256 && tid < 512) {
        const int t = tid - 256;               // 0..255
        const int buf = t >> 7, hl = (t >> 6) & 1, u = t & 63;
        const int row = u >> 2, q = u & 3;
        const int col = (112 + q * 4) ^ ((row & 7) << 3);
        short* dst = hl ? h2L : h2H;
        s16x4 z = 0;
        *(s16x4*)(dst + buf * 2048 + row * 128 + col) = z;
    }

    // ---- per-thread w1 coeffs (gen role: row=tid>>5, k0=(tid&31)*4) ----
    const int grow = tid >> 5;
    const int k0   = (tid & 31) * 4;
    f32x4 c1_0, c1_1, c1_2, c1_3;
    #define LDC(J, C) do { const int k = k0 + (J);                              \
        if (k < 120) { C.x = pw1[k*3]; C.y = pw1[k*3+1]; C.z = pw1[k*3+2];      \
                       C.w = pb1[k]; }                                          \
        else C = 0.f; } while (0)
    LDC(0, c1_0); LDC(1, c1_1); LDC(2, c1_2); LDC(3, c1_3);
    #undef LDC

    // ---- stationary weight frags (A-operand): w2 for w<7, w3 for w<5 ----
    const int arow = 16 * w + ln;
    s16x8 w2h0=0,w2h1=0,w2h2=0,w2h3=0, w2l0=0,w2l1=0,w2l2=0,w2l3=0;
    s16x8 w3h0=0,w3h1=0,w3h2=0,w3h3=0, w3l0=0,w3l1=0,w3l2=0,w3l3=0;
    f32x4 bb2 = 0.f, bb3 = 0.f;
    if (w < 7) {
        #define LDW2(KS, DH, DL) do { s16x8 vh, vl;                             \
            _Pragma("unroll")                                                   \
            for (int j = 0; j < 8; ++j) {                                       \
                const int c = (KS) * 32 + l4 * 8 + j;                           \
                float v = (arow < 100 && c < 120) ? pw2[arow * 120 + c] : 0.f;  \
                short hi, lo; bsplit(v, hi, lo); vh[j] = hi; vl[j] = lo;        \
            } DH = vh; DL = vl; } while (0)
        LDW2(0, w2h0, w2l0); LDW2(1, w2h1, w2l1);
        LDW2(2, w2h2, w2l2); LDW2(3, w2h3, w2l3);
        #undef LDW2
        const int o0 = 16 * w + 4 * l4;
        #pragma unroll
        for (int r = 0; r < 4; ++r) bb2[r] = (o0 + r < 100) ? pb2[o0 + r] : 0.f;
    }
    if (w < 5) {
        #define LDW3(KS, DH, DL) do { s16x8 vh, vl;                             \
            _Pragma("unroll")                                                   \
            for (int j = 0; j < 8; ++j) {                                       \
                const int c = (KS) * 32 + l4 * 8 + j;                           \
                float v = (c < 100) ? pw3[arow * 100 + c] : 0.f;                \
                short hi, lo; bsplit(v, hi, lo); vh[j] = hi; vl[j] = lo;        \
            } DH = vh; DL = vl; } while (0)
        LDW3(0, w3h0, w3l0); LDW3(1, w3h1, w3l1);
        LDW3(2, w3h2, w3l2); LDW3(3, w3h3, w3l3);
        #undef LDW3
        bb3 = *(const f32x4*)(pb3 + 16 * w + 4 * l4);
    }
    __syncthreads();

    float pool0 = 0.f, pool1 = 0.f, pool2 = 0.f, pool3 = 0.f;
    const int swzR = (ln & 7) << 3;         // read-side swizzle (row = ln)
    const int swzG = (grow & 7) << 3;       // gen-side swizzle  (row = grow)

    // ---- 3-stage pipeline: phase T: gen(T) || L2(T-1) || L3(T-2), 1 barrier ----
    #pragma unroll 1
    for (int T = 0; T < 10; ++T) {
        const int bufA = (T & 1) << 11;      // gen h1 dst; L3 h2 src ((T-2)&1)
        const int bufB = 2048 - bufA;        // L2 h1 src / h2 dst   ((T-1)&1)

        // gen tile T -> h1[bufA]
        if (T < 8) {
            const int el = 16 * T + grow;
            const float x0 = xs[el * 3], x1 = xs[el * 3 + 1], x2 = xs[el * 3 + 2];
            s16x4 vh, vl;
            #define GEN(J, C) do {                                              \
                float v = fmaf(x0, C.x, fmaf(x1, C.y, fmaf(x2, C.z, C.w)));     \
                v = fmaxf(v, 0.f);                                              \
                short hi, lo; bsplit(v, hi, lo); vh[J] = hi; vl[J] = lo;        \
            } while (0)
            GEN(0, c1_0); GEN(1, c1_1); GEN(2, c1_2); GEN(3, c1_3);
            #undef GEN
            const int idx = bufA + grow * 128 + (k0 ^ swzG);
            *(s16x4*)(h1H + idx) = vh;
            *(s16x4*)(h1L + idx) = vl;
        }

        // L2 tile T-1: h1[bufB] -> h2[bufB]
        if (w < 7 && T >= 1 && T <= 8) {
            f32x4 a2h = 0.f, a2x = 0.f;
            #define L2K(KS, WH, WL) do {                                        \
                const int bidx = bufB + ln * 128 + (((KS) * 32 + l4 * 8) ^ swzR);\
                const s16x8 bh = *(const s16x8*)(h1H + bidx);                   \
                const s16x8 bl = *(const s16x8*)(h1L + bidx);                   \
                a2h = MFMA_B16(WH, bh, a2h);                                    \
                a2x = MFMA_B16(WH, bl, a2x);                                    \
                a2x = MFMA_B16(WL, bh, a2x);                                    \
            } while (0)
            L2K(0, w2h0, w2l0); L2K(1, w2h1, w2l1);
            L2K(2, w2h2, w2l2); L2K(3, w2h3, w2l3);
            #undef L2K
            s16x4 oh, ol;
            #pragma unroll
            for (int r = 0; r < 4; ++r) {
                float v = fmaxf(a2h[r] + a2x[r] + bb2[r], 0.f);
                short hi, lo; bsplit(v, hi, lo);
                oh[r] = hi; ol[r] = lo;
            }
            const int idx2 = bufB + ln * 128 + ((16 * w + 4 * l4) ^ swzR);
            *(s16x4*)(h2H + idx2) = oh;
            *(s16x4*)(h2L + idx2) = ol;
        }

        // L3 tile T-2: h2[bufA] -> pool regs
        if (w < 5 && T >= 2) {
            f32x4 a3 = 0.f, a3x = 0.f;
            #define L3K(KS, WH, WL) do {                                        \
                const int bidx = bufA + ln * 128 + (((KS) * 32 + l4 * 8) ^ swzR);\
                const s16x8 bh = *(const s16x8*)(h2H + bidx);                   \
                const s16x8 bl = *(const s16x8*)(h2L + bidx);                   \
                a3  = MFMA_B16(WH, bh, a3);                                     \
                a3x = MFMA_B16(WH, bl, a3x);                                    \
                a3x = MFMA_B16(WL, bh, a3x);                                    \
            } while (0)
            L3K(0, w3h0, w3l0); L3K(1, w3h1, w3l1);
            L3K(2, w3h2, w3l2); L3K(3, w3h3, w3l3);
            #undef L3K
            pool0 += fmaxf(a3[0] + a3x[0] + bb3[0], 0.f);
            pool1 += fmaxf(a3[1] + a3x[1] + bb3[1], 0.f);
            pool2 += fmaxf(a3[2] + a3x[2] + bb3[2], 0.f);
            pool3 += fmaxf(a3[3] + a3x[3] + bb3[3], 0.f);
        }
        __syncthreads();
    }

    // ---- pool reduce over ln, write pooledS ----
    if (w < 5) {
        #pragma unroll
        for (int d = 1; d < 16; d <<= 1) {
            pool0 += __shfl_xor(pool0, d);
            pool1 += __shfl_xor(pool1, d);
            pool2 += __shfl_xor(pool2, d);
            pool3 += __shfl_xor(pool3, d);
        }
        if (ln == 0) {
            const int o0 = 16 * w + 4 * l4;
            pooledS[o0 + 0] = pool0;
            pooledS[o0 + 1] = pool1;
            pooledS[o0 + 2] = pool2;
            pooledS[o0 + 3] = pool3;
        }
    }
    __syncthreads();

    // ---- fused tail (R10-verified) ----
    if (tid < 60) {
        float a = rb1[tid];
        for (int k = 0; k < 80; k += 4) {
            f32x4 pv = *(const f32x4*)(pooledS + k);
            f32x4 wv = *(const f32x4*)(rw1 + tid * 80 + k);
            a += pv.x * wv.x + pv.y * wv.y + pv.z * wv.z + pv.w * wv.w;
        }
        r1s[tid] = fmaxf(a, 0.0f);
    }
    __syncthreads();
    if (tid < 60) {
        float a = rb2[tid];
        for (int k = 0; k < 60; k += 4) {
            f32x4 pv = *(const f32x4*)(r1s + k);
            f32x4 wv = *(const f32x4*)(rw2 + tid * 60 + k);
            a += pv.x * wv.x + pv.y * wv.y + pv.z * wv.z + pv.w * wv.w;
        }
        r2s[tid] = fmaxf(a, 0.0f);
    }
    __syncthreads();
    if (tid < 40) {
        float a = rb3[tid];
        for (int k = 0; k < 60; k += 4) {
            f32x4 pv = *(const f32x4*)(r2s + k);
            f32x4 wv = *(const f32x4*)(rw3 + tid * 60 + k);
            a += pv.x * wv.x + pv.y * wv.y + pv.z * wv.z + pv.w * wv.w;
        }
        xcat[tid] = a;
    }
    if (tid >= 40 && tid < 43) xcat[tid] = stat[(size_t)b * 3 + (tid - 40)];
    __syncthreads();
    if (tid < 200) {
        float a = qb1[tid];
        const float* wv = qw1 + tid * 43;
        for (int k = 0; k < 43; ++k) a += xcat[k] * wv[k];
        q1s[tid] = fmaxf(a, 0.0f);
    }
    __syncthreads();
    if (tid < 100) {
        float a = qb2[tid];
        for (int k = 0; k < 200; k += 4) {
            f32x4 pv = *(const f32x4*)(q1s + k);
            f32x4 wv = *(const f32x4*)(qw2 + tid * 200 + k);
            a += pv.x * wv.x + pv.y * wv.y + pv.z * wv.z + pv.w * wv.w;
        }
        q2s[tid] = fmaxf(a, 0.0f);
    }
    __syncthreads();
    if (tid < 96) {
        int o = tid >> 5, l2 = tid & 31;
        float a = 0.0f;
        for (int k = l2; k < 100; k += 32) a += q2s[k] * qw3[o * 100 + k];
        #pragma unroll
        for (int d = 16; d > 0; d >>= 1) a += __shfl_down(a, d, 32);
        if (l2 == 0) logits[o] = a + qb3[o];
    }
    __syncthreads();
    if (tid < 3) {
        float l0 = logits[0], l1 = logits[1], l2v = logits[2];
        float m  = fmaxf(l0, fmaxf(l1, l2v));
        float e0 = __expf(l0 - m), e1 = __expf(l1 - m), e2 = __expf(l2v - m);
        float inv = 1.0f / (e0 + e1 + e2);
        float mine = (tid == 0) ? e0 : ((tid == 1) ? e1 : e2);
        out[(size_t)b * 3 + tid] = mine * inv;
    }
}

extern "C" void kernel_launch(void* const* d_in, const int* in_sizes, int n_in,
                              void* d_out, int out_size, void* d_ws, size_t ws_size,
                              hipStream_t stream) {
    const float* dyn  = (const float*)d_in[0];
    const float* stat = (const float*)d_in[1];
    const float* pw1  = (const float*)d_in[2];
    const float* pb1  = (const float*)d_in[3];
    const float* pw2  = (const float*)d_in[4];
    const float* pb2  = (const float*)d_in[5];
    const float* pw3  = (const float*)d_in[6];
    const float* pb3  = (const float*)d_in[7];
    const float* rw1  = (const float*)d_in[8];
    const float* rb1  = (const float*)d_in[9];
    const float* rw2  = (const float*)d_in[10];
    const float* rb2  = (const float*)d_in[11];
    const float* rw3  = (const float*)d_in[12];
    const float* rb3  = (const float*)d_in[13];
    const float* qw1  = (const float*)d_in[14];
    const float* qb1  = (const float*)d_in[15];
    const float* qw2  = (const float*)d_in[16];
    const float* qb2  = (const float*)d_in[17];
    const float* qw3  = (const float*)d_in[18];
    const float* qb3  = (const float*)d_in[19];
    float* out = (float*)d_out;

    const int B = in_sizes[0] / 384;   // 2048
    ds_all<<<dim3(B), dim3(512), 0, stream>>>(dyn, stat,
        pw1, pb1, pw2, pb2, pw3, pb3,
        rw1, rb1, rw2, rb2, rw3, rb3,
        qw1, qb1, qw2, qb2, qw3, qb3, out);
}